// Round 12
// baseline (746.857 us; speedup 1.0000x reference)
//
#include <hip/hip_runtime.h>

// ---------------------------------------------------------------------------
// KeyValueMemoryRecallNet, R7 (6th submit; prior rounds: 5x broker timeout,
// 1x container failure — this source has never reached hardware).
//   - 128 blocks x 128 threads (2 waves). Each wave runs TWO independent
//     4-row recurrence chains (A: rows 4q4+w, B: rows 4q4+w+2). In-order
//     waves can't fill dependency bubbles of one chain (R6: 1393 cyc/step,
//     only ~40% issuing); the sibling chain's stream fills the gaps.
//   - retr eliminated: GV[s][g] = VA[s]*wih64[g] + VB[s]*wih65[g] pre-folded,
//     softmax weights a_s feed gates directly (3 fma); brc folded into biasQ.
//   - Steady softmax drops max-subtraction (|p| <~ 2, exp-safe, identical
//     math); prologue keeps the masked -1e30 form.
//   - Direct per-step global stores (vmcnt in-order; store buffers wasted
//     48 VGPRs for nothing).
//   - Carries R6: sigma-order bpermute h-transport, 4-steps-per-MFMA xa
//     packing, persistent C-quads.
//
// MFMA 16x16x32 bf16 layouts (validated in R1):
//   A-frag: lane l holds A[row = l%16][k-slot j]
//   B-frag: lane l holds B[k-slot j][col = l%16]
//   C/D   : lane l holds D[row = 4*(l/16)+r][col = l%16]
// sigma k-order (h path): slot j of lane (q4,c) <-> k = 4*q4 + (j>>1) + 16*(j&1).
// bpermute: dest lane (q4,c) pulls f_i from source lane 16*(c>>2)+4*q4+i, which
// holds pack(h[4*(c>>2)+ww][4q4+i], h[...][4q4+i+16]) for chain offset ww ->
// A[row c] = h[4*(c>>2)+ww], D[4q4+r][c] = gh[own row 4q4+ww][col c], comp 0.
// ---------------------------------------------------------------------------

typedef __attribute__((ext_vector_type(4))) float f32x4;
typedef __attribute__((ext_vector_type(8))) __bf16 bf16x8;

#define NB 2048
#define SL 512
#define NIN 64
#define NH 32
#define NO 16

__device__ __forceinline__ float rcpf_(float x) { return __builtin_amdgcn_rcpf(x); }
__device__ __forceinline__ float sigmoidf_(float x) {
  return rcpf_(1.0f + __expf(-x));
}
__device__ __forceinline__ float tanhf_(float x) {
  return 1.0f - 2.0f * rcpf_(__expf(2.0f * x) + 1.0f);
}
__device__ __forceinline__ f32x4 splat4(float v) {
  f32x4 r; r[0] = v; r[1] = v; r[2] = v; r[3] = v; return r;
}

// DPP rotate-add reduction within each 16-lane row (groups == same l>>4).
template <int CTRL>
__device__ __forceinline__ float dpp_add_(float v) {
  int p = __builtin_amdgcn_update_dpp(0, __float_as_int(v), CTRL, 0xF, 0xF, true);
  return v + __int_as_float(p);
}
__device__ __forceinline__ float rowsum16(float v) {
  v = dpp_add_<0x121>(v);  // row_ror:1
  v = dpp_add_<0x122>(v);  // row_ror:2
  v = dpp_add_<0x124>(v);  // row_ror:4
  v = dpp_add_<0x128>(v);  // row_ror:8
  return v;
}

__device__ __forceinline__ uint32_t cvtpk_(float lo, float hi) {
  uint32_t r;
  asm("v_cvt_pk_bf16_f32 %0, %1, %2" : "=v"(r) : "v"(lo), "v"(hi));
  return r;
}

__device__ __forceinline__ bf16x8 frag4(uint32_t a, uint32_t b, uint32_t c, uint32_t d) {
  union { uint32_t u[4]; bf16x8 v; } x;
  x.u[0] = a; x.u[1] = b; x.u[2] = c; x.u[3] = d;
  return x.v;
}

// uniform-ww component picks (one-time / prologue only)
__device__ __forceinline__ float pick4v(f32x4 v, int ww) {
  float a = (ww & 2) ? v[2] : v[0];
  float b = (ww & 2) ? v[3] : v[1];
  return (ww & 1) ? b : a;
}
__device__ __forceinline__ float pick4f(float a0, float a1, float a2, float a3, int ww) {
  float a = (ww & 2) ? a2 : a0;
  float b = (ww & 2) ? a3 : a1;
  return (ww & 1) ? b : a;
}

// standard-order B-frag of W^T (y = x @ W^T): B[k][col] = W[col][k].
__device__ __forceinline__ bf16x8 ldfrag(const float* __restrict__ W, int indim,
                                         int row, int k0) {
  bf16x8 r;
#pragma unroll
  for (int j = 0; j < 8; ++j) {
    int k = k0 + j;
    float w = (k < indim) ? W[row * indim + k] : 0.0f;
    r[j] = (__bf16)w;
  }
  return r;
}
// sigma-order B-frag (indim==32): slot j -> k = 4*q4 + (j>>1) + ((j&1) ? 16 : 0)
__device__ __forceinline__ bf16x8 ldfragS(const float* __restrict__ W, int row, int q4) {
  bf16x8 r;
#pragma unroll
  for (int j = 0; j < 8; ++j) {
    int k = 4 * q4 + (j >> 1) + ((j & 1) ? 16 : 0);
    r[j] = (__bf16)W[row * 32 + k];
  }
  return r;
}
// B-frag of W (y = x @ W): B[k][col] = W[k][col].
__device__ __forceinline__ bf16x8 ldfragT(const float* __restrict__ W, int ncol,
                                          int col, int k0) {
  bf16x8 r;
#pragma unroll
  for (int j = 0; j < 8; ++j) r[j] = (__bf16)W[(k0 + j) * ncol + col];
  return r;
}

#define MFMA(A, B, C) __builtin_amdgcn_mfma_f32_16x16x32_bf16((A), (B), (C), 0, 0, 0)

__global__ __launch_bounds__(128, 1)
void kvmr_kernel(const float* __restrict__ inputs,   // [2048][512][64]
                 const float* __restrict__ w_ih,     // [96][66]
                 const float* __restrict__ w_hh,     // [96][32]
                 const float* __restrict__ b_ih,     // [96]
                 const float* __restrict__ b_hh,     // [96]
                 const float* __restrict__ W_key,    // [64][32]
                 const float* __restrict__ b_key,    // [64]
                 const float* __restrict__ W_query,  // [64][32]
                 const float* __restrict__ b_query,  // [64]
                 const float* __restrict__ W_value,  // [64][32]
                 const float* __restrict__ b_value,  // [64]
                 const float* __restrict__ W_recall, // [2][64]
                 const float* __restrict__ b_recall, // [2]
                 const float* __restrict__ W_out,    // [16][32]
                 const float* __restrict__ b_out,    // [16]
                 float* __restrict__ out_all) {      // outputs | hiddens
  const int tid = threadIdx.x;
  const int l  = tid & 63;
  const int c  = l & 15;
  const int q4 = l >> 4;
  const int w  = tid >> 6;       // wave id in {0,1}
  const int wA = w;              // chain A row offset
  const int wB = w + 2;          // chain B row offset
  const int b0 = blockIdx.x * 16;

  __shared__ __align__(16) uint32_t h_pk[2][16 * 16];      // per-wave prologue relay (packed)
  __shared__ __align__(16) __bf16 kv_pro[2][3][16 * 64];   // per-wave fold relay

  // ---- weights as register-resident B-fragments ----
  bf16x8 Bih[6][2];       // standard order (A = x from global, standard k)
  bf16x8 BhhS[6];         // sigma order (A = h via bpermute/packed relay)
#pragma unroll
  for (int g = 0; g < 6; ++g) {
#pragma unroll
    for (int kc = 0; kc < 2; ++kc)
      Bih[g][kc] = ldfrag(w_ih, 66, 16 * g + c, 32 * kc + 8 * q4);
    BhhS[g] = ldfragS(w_hh, 16 * g + c, q4);
  }
  bf16x8 BqS[4], BkS[4], BvS[4];
#pragma unroll
  for (int g = 0; g < 4; ++g) {
    BqS[g] = ldfragS(W_query, 16 * g + c, q4);
    BkS[g] = ldfragS(W_key,   16 * g + c, q4);
    BvS[g] = ldfragS(W_value, 16 * g + c, q4);
  }
  bf16x8 BoS = ldfragS(W_out, c, q4);

  float wih64[6], wih65[6];
#pragma unroll
  for (int g = 0; g < 6; ++g) {
    wih64[g] = w_ih[(16 * g + c) * 66 + 64];
    wih65[g] = w_ih[(16 * g + c) * 66 + 65];
  }
  float wr0f[4], wr1f[4];
#pragma unroll
  for (int g = 0; g < 4; ++g) {
    wr0f[g] = W_recall[16 * g + c];
    wr1f[g] = W_recall[64 + 16 * g + c];
  }

  float bias_rz[4], bias_xn[2], bias_hn[2];
#pragma unroll
  for (int g = 0; g < 4; ++g) bias_rz[g] = b_ih[16 * g + c] + b_hh[16 * g + c];
#pragma unroll
  for (int gg = 0; gg < 2; ++gg) {
    bias_xn[gg] = b_ih[64 + 16 * gg + c];
    bias_hn[gg] = b_hh[64 + 16 * gg + c];
  }
  float bq4[4], bk4[4], bv4[4];
#pragma unroll
  for (int g = 0; g < 4; ++g) {
    bq4[g] = b_query[16 * g + c];
    bk4[g] = b_key[16 * g + c];
    bv4[g] = b_value[16 * g + c];
  }
  float bo1 = b_out[c];
  float br0 = b_recall[0], br1 = b_recall[1];

  float* outWA = out_all + (size_t)(b0 + 4 * q4 + wA) * SL * NO + c;
  float* hidWA = out_all + (size_t)NB * SL * NO + (size_t)(b0 + 4 * q4 + wA) * SL * NH + c;
  float* outWB = out_all + (size_t)(b0 + 4 * q4 + wB) * SL * NO + c;
  float* hidWB = out_all + (size_t)NB * SL * NO + (size_t)(b0 + 4 * q4 + wB) * SL * NH + c;

  // ---- prologue state ----
  f32x4 hD0 = splat4(0.0f), hD1 = splat4(0.0f);
  f32x4 keysR[3][4], valsR[3][4];
#pragma unroll
  for (int s = 0; s < 3; ++s)
#pragma unroll
    for (int g = 0; g < 4; ++g) { keysR[s][g] = splat4(0.0f); valsR[s][g] = splat4(0.0f); }

  f32x4 hPartRZ[4], hPartHN[2];
#pragma unroll
  for (int g = 0; g < 4; ++g) hPartRZ[g] = splat4(bias_rz[g]);
#pragma unroll
  for (int gg = 0; gg < 2; ++gg) hPartHN[gg] = splat4(bias_hn[gg]);
  float retr0c[4] = {0.f, 0.f, 0.f, 0.f};
  float retr1c[4] = {0.f, 0.f, 0.f, 0.f};

  // ---- prologue x double prefetch (rows b0+c; all 16 rows genuine) ----
  const float* xp = inputs + (size_t)(b0 + c) * (SL * NIN) + 8 * q4;
  f32x4 xb[2][4];
#pragma unroll
  for (int p = 0; p < 2; ++p) {
    const float* xq = xp + p * NIN;
    xb[p][0] = *(const f32x4*)(xq + 0);
    xb[p][1] = *(const f32x4*)(xq + 4);
    xb[p][2] = *(const f32x4*)(xq + 32);
    xb[p][3] = *(const f32x4*)(xq + 36);
  }

  // =========================================================================
  // Prologue: t = 0,1,2 — redundant per wave, private LDS, no sync.
  // =========================================================================
#pragma unroll
  for (int t = 0; t < 3; ++t) {
    const int pb = t & 1;
    bf16x8 ax0, ax1;
#pragma unroll
    for (int j = 0; j < 4; ++j) {
      ax0[j]     = (__bf16)xb[pb][0][j];
      ax0[4 + j] = (__bf16)xb[pb][1][j];
      ax1[j]     = (__bf16)xb[pb][2][j];
      ax1[4 + j] = (__bf16)xb[pb][3][j];
    }
    {
      const float* xq = xp + (t + 2) * NIN;
      xb[pb][0] = *(const f32x4*)(xq + 0);
      xb[pb][1] = *(const f32x4*)(xq + 4);
      xb[pb][2] = *(const f32x4*)(xq + 32);
      xb[pb][3] = *(const f32x4*)(xq + 36);
    }

    f32x4 accRZ[4], accXN[2];
#pragma unroll
    for (int g = 0; g < 4; ++g) {
      f32x4 a = hPartRZ[g];
#pragma unroll
      for (int r = 0; r < 4; ++r) a[r] += retr0c[r] * wih64[g] + retr1c[r] * wih65[g];
      a = MFMA(ax0, Bih[g][0], a);
      a = MFMA(ax1, Bih[g][1], a);
      accRZ[g] = a;
    }
#pragma unroll
    for (int gg = 0; gg < 2; ++gg) {
      f32x4 a = splat4(bias_xn[gg]);
#pragma unroll
      for (int r = 0; r < 4; ++r) a[r] += retr0c[r] * wih64[4 + gg] + retr1c[r] * wih65[4 + gg];
      a = MFMA(ax0, Bih[4 + gg][0], a);
      a = MFMA(ax1, Bih[4 + gg][1], a);
      accXN[gg] = a;
    }

    f32x4 hn0, hn1;
#pragma unroll
    for (int r = 0; r < 4; ++r) {
      float rg0 = sigmoidf_(accRZ[0][r]);
      float zg0 = sigmoidf_(accRZ[2][r]);
      float ng0 = tanhf_(accXN[0][r] + rg0 * hPartHN[0][r]);
      hn0[r] = (1.0f - zg0) * ng0 + zg0 * hD0[r];
      float rg1 = sigmoidf_(accRZ[1][r]);
      float zg1 = sigmoidf_(accRZ[3][r]);
      float ng1 = tanhf_(accXN[1][r] + rg1 * hPartHN[1][r]);
      hn1[r] = (1.0f - zg1) * ng1 + zg1 * hD1[r];
    }
    hD0 = hn0; hD1 = hn1;

    hidWA[t * NH]      = pick4v(hn0, wA);
    hidWA[t * NH + 16] = pick4v(hn1, wA);
    hidWB[t * NH]      = pick4v(hn0, wB);
    hidWB[t * NH + 16] = pick4v(hn1, wB);
    // packed sigma relay: write pair u32, read b128 of 4 consecutive pairs
#pragma unroll
    for (int r = 0; r < 4; ++r)
      h_pk[w][(4 * q4 + r) * 16 + c] = cvtpk_(hn0[r], hn1[r]);
    bf16x8 hA = *(const bf16x8*)&h_pk[w][c * 16 + 4 * q4];

#pragma unroll
    for (int g = 0; g < 4; ++g) hPartRZ[g] = MFMA(hA, BhhS[g], splat4(bias_rz[g]));
#pragma unroll
    for (int gg = 0; gg < 2; ++gg) hPartHN[gg] = MFMA(hA, BhhS[4 + gg], splat4(bias_hn[gg]));
    f32x4 oT = MFMA(hA, BoS, splat4(bo1));
    outWA[t * NO] = pick4v(oT, wA);
    outWB[t * NO] = pick4v(oT, wB);

    f32x4 qT[4], kT[4], vT[4];
#pragma unroll
    for (int g = 0; g < 4; ++g) {
      qT[g] = MFMA(hA, BqS[g], splat4(bq4[g]));
      kT[g] = MFMA(hA, BkS[g], splat4(bk4[g]));
      vT[g] = MFMA(hA, BvS[g], splat4(bv4[g]));
    }

    // attention over slots < t (scores on pre-write memory); keep max form here
#pragma unroll
    for (int r = 0; r < 4; ++r) {
      float d0 = qT[0][r] * keysR[0][0][r] + qT[1][r] * keysR[0][1][r] +
                 qT[2][r] * keysR[0][2][r] + qT[3][r] * keysR[0][3][r];
      float d1 = qT[0][r] * keysR[1][0][r] + qT[1][r] * keysR[1][1][r] +
                 qT[2][r] * keysR[1][2][r] + qT[3][r] * keysR[1][3][r];
      float s0 = (t > 0) ? rowsum16(d0) : -1e30f;
      float s1 = (t > 1) ? rowsum16(d1) : -1e30f;
      float s2 = -1e30f;
      float mx = fmaxf(s0, fmaxf(s1, s2));
      float e0 = __expf(s0 - mx), e1 = __expf(s1 - mx), e2 = __expf(s2 - mx);
      float inv = rcpf_(e0 + e1 + e2);
      float u0 = 0.f, u1 = 0.f;
#pragma unroll
      for (int g = 0; g < 4; ++g) {
        float rd = (e0 * valsR[0][g][r] + e1 * valsR[1][g][r] + e2 * valsR[2][g][r]) * inv;
        u0 += rd * wr0f[g];
        u1 += rd * wr1f[g];
      }
      u0 = rowsum16(u0);
      u1 = rowsum16(u1);
      retr0c[r] = (t > 0) ? (u0 + br0) : 0.0f;
      retr1c[r] = (t > 0) ? (u1 + br1) : 0.0f;
    }

#pragma unroll
    for (int g = 0; g < 4; ++g) { keysR[t][g] = kT[g]; valsR[t][g] = vT[g]; }
  }

  // =========================================================================
  // Fold (memory frozen after t=2): M = keys@Wq, Cq = bq.keys, VR = vals.Wr^T
  // =========================================================================
#pragma unroll
  for (int s = 0; s < 3; ++s)
#pragma unroll
    for (int g = 0; g < 4; ++g)
#pragma unroll
      for (int r = 0; r < 4; ++r)
        kv_pro[w][s][(4 * q4 + r) * 64 + 16 * g + c] = (__bf16)keysR[s][g][r];

  bf16x8 Bwq[2][2];
#pragma unroll
  for (int ch = 0; ch < 2; ++ch)
#pragma unroll
    for (int ct = 0; ct < 2; ++ct)
      Bwq[ch][ct] = ldfragT(W_query, 32, 16 * ct + c, 32 * ch + 8 * q4);

  float M0c[3][4], M1c[3][4], Cq[3][4], VRa[3][4], VRb[3][4];
#pragma unroll
  for (int s = 0; s < 3; ++s) {
    const bf16x8 ak0 = *(const bf16x8*)&kv_pro[w][s][c * 64 + 8 * q4];
    const bf16x8 ak1 = *(const bf16x8*)&kv_pro[w][s][c * 64 + 32 + 8 * q4];
    f32x4 m0 = MFMA(ak1, Bwq[1][0], MFMA(ak0, Bwq[0][0], splat4(0.0f)));
    f32x4 m1 = MFMA(ak1, Bwq[1][1], MFMA(ak0, Bwq[0][1], splat4(0.0f)));
#pragma unroll
    for (int r = 0; r < 4; ++r) {
      M0c[s][r] = m0[r];
      M1c[s][r] = m1[r];
      Cq[s][r] = rowsum16(keysR[s][0][r] * bq4[0] + keysR[s][1][r] * bq4[1] +
                          keysR[s][2][r] * bq4[2] + keysR[s][3][r] * bq4[3]);
      VRa[s][r] = rowsum16(valsR[s][0][r] * wr0f[0] + valsR[s][1][r] * wr0f[1] +
                           valsR[s][2][r] * wr0f[2] + valsR[s][3][r] * wr0f[3]);
      VRb[s][r] = rowsum16(valsR[s][0][r] * wr1f[0] + valsR[s][1][r] * wr1f[1] +
                           valsR[s][2][r] * wr1f[2] + valsR[s][3][r] * wr1f[3]);
    }
  }

  // ---- per-chain W slices ----
  float Ma0[3], Ma1[3], Cqa[3], VAa[3], VBa[3];
  float Mb0[3], Mb1[3], Cqb[3], VAb[3], VBb[3];
#pragma unroll
  for (int s = 0; s < 3; ++s) {
    Ma0[s] = pick4f(M0c[s][0], M0c[s][1], M0c[s][2], M0c[s][3], wA);
    Ma1[s] = pick4f(M1c[s][0], M1c[s][1], M1c[s][2], M1c[s][3], wA);
    Cqa[s] = pick4f(Cq[s][0],  Cq[s][1],  Cq[s][2],  Cq[s][3],  wA);
    VAa[s] = pick4f(VRa[s][0], VRa[s][1], VRa[s][2], VRa[s][3], wA);
    VBa[s] = pick4f(VRb[s][0], VRb[s][1], VRb[s][2], VRb[s][3], wA);
    Mb0[s] = pick4f(M0c[s][0], M0c[s][1], M0c[s][2], M0c[s][3], wB);
    Mb1[s] = pick4f(M1c[s][0], M1c[s][1], M1c[s][2], M1c[s][3], wB);
    Cqb[s] = pick4f(Cq[s][0],  Cq[s][1],  Cq[s][2],  Cq[s][3],  wB);
    VAb[s] = pick4f(VRa[s][0], VRa[s][1], VRa[s][2], VRa[s][3], wB);
    VBb[s] = pick4f(VRb[s][0], VRb[s][1], VRb[s][2], VRb[s][3], wB);
  }

  // ---- GV fold: retr contribution to gate g from softmax weight a_s ----
  float GVa[3][6], GVb[3][6], brc[6];
#pragma unroll
  for (int g = 0; g < 6; ++g) {
    brc[g] = br0 * wih64[g] + br1 * wih65[g];
#pragma unroll
    for (int s = 0; s < 3; ++s) {
      GVa[s][g] = VAa[s] * wih64[g] + VBa[s] * wih65[g];
      GVb[s][g] = VAb[s] * wih64[g] + VBb[s] * wih65[g];
    }
  }

  // ---- persistent MFMA C-quads (brc folded into biasQ) ----
  const f32x4 Zq = splat4(0.0f);
  f32x4 biasQ[6];
#pragma unroll
  for (int g = 0; g < 4; ++g) biasQ[g] = splat4(bias_rz[g] + brc[g]);
  biasQ[4] = splat4(bias_xn[0] + brc[4]);
  biasQ[5] = splat4(bias_xn[1] + brc[5]);
  const f32x4 bhnQ0 = splat4(bias_hn[0]);
  const f32x4 bhnQ1 = splat4(bias_hn[1]);
  const f32x4 boQ   = splat4(bo1);

  // ---- t = 3 closed form (h_3 flushed to 0) ----
  hidWA[3 * NH] = 0.0f; hidWA[3 * NH + 16] = 0.0f; outWA[3 * NO] = bo1;
  hidWB[3 * NH] = 0.0f; hidWB[3 * NH + 16] = 0.0f; outWB[3 * NO] = bo1;

  float aa0, aa1, aa2, ab0, ab1, ab2;
  {
    float e0 = __expf(Cqa[0]), e1 = __expf(Cqa[1]), e2 = __expf(Cqa[2]);
    float inv = rcpf_(e0 + e1 + e2);
    aa0 = e0 * inv; aa1 = e1 * inv; aa2 = e2 * inv;
  }
  {
    float e0 = __expf(Cqb[0]), e1 = __expf(Cqb[1]), e2 = __expf(Cqb[2]);
    float inv = rcpf_(e0 + e1 + e2);
    ab0 = e0 * inv; ab1 = e1 * inv; ab2 = e2 * inv;
  }

  float hprzA0 = 0.f, hprzA1 = 0.f, hprzA2 = 0.f, hprzA3 = 0.f;
  float hphnA0 = bias_hn[0], hphnA1 = bias_hn[1];
  float hA0p = 0.f, hA1p = 0.f;
  float hprzB0 = 0.f, hprzB1 = 0.f, hprzB2 = 0.f, hprzB3 = 0.f;
  float hphnB0 = bias_hn[0], hphnB1 = bias_hn[1];
  float hB0p = 0.f, hB1p = 0.f;

  // bpermute source-lane byte indices (lane-geometric; shared by both chains)
  const int bp0 = 4 * (16 * ((l >> 2) & 3) + 4 * (l >> 4));
  const int bp1 = bp0 + 4;
  const int bp2 = bp0 + 8;
  const int bp3 = bp0 + 12;

  // ---- per-chain x pipelines ----
  const float* xgpA = inputs + (size_t)(b0 + 4 * (c >> 2) + wA) * (SL * NIN) +
                      (size_t)(c & 3) * NIN + 8 * q4;
  const float* xgpB = inputs + (size_t)(b0 + 4 * (c >> 2) + wB) * (SL * NIN) +
                      (size_t)(c & 3) * NIN + 8 * q4;
  f32x4 xgA[4], xgB[4];
#define LOADXGA(T) {                                                          \
    const float* q_ = xgpA + (size_t)(T) * NIN;                               \
    xgA[0] = *(const f32x4*)(q_ + 0);                                         \
    xgA[1] = *(const f32x4*)(q_ + 4);                                         \
    xgA[2] = *(const f32x4*)(q_ + 32);                                        \
    xgA[3] = *(const f32x4*)(q_ + 36);                                        \
  }
#define LOADXGB(T) {                                                          \
    const float* q_ = xgpB + (size_t)(T) * NIN;                               \
    xgB[0] = *(const f32x4*)(q_ + 0);                                         \
    xgB[1] = *(const f32x4*)(q_ + 4);                                         \
    xgB[2] = *(const f32x4*)(q_ + 32);                                        \
    xgB[3] = *(const f32x4*)(q_ + 36);                                        \
  }
#define XACOMPA(DST) {                                                        \
    bf16x8 ax0, ax1;                                                          \
    _Pragma("unroll") for (int j = 0; j < 4; ++j) {                           \
      ax0[j]     = (__bf16)xgA[0][j];                                         \
      ax0[4 + j] = (__bf16)xgA[1][j];                                         \
      ax1[j]     = (__bf16)xgA[2][j];                                         \
      ax1[4 + j] = (__bf16)xgA[3][j];                                         \
    }                                                                         \
    _Pragma("unroll") for (int g = 0; g < 6; ++g)                             \
      DST[g] = MFMA(ax1, Bih[g][1], MFMA(ax0, Bih[g][0], biasQ[g]));          \
  }
#define XACOMPB(DST) {                                                        \
    bf16x8 ax0, ax1;                                                          \
    _Pragma("unroll") for (int j = 0; j < 4; ++j) {                           \
      ax0[j]     = (__bf16)xgB[0][j];                                         \
      ax0[4 + j] = (__bf16)xgB[1][j];                                         \
      ax1[j]     = (__bf16)xgB[2][j];                                         \
      ax1[4 + j] = (__bf16)xgB[3][j];                                         \
    }                                                                         \
    _Pragma("unroll") for (int g = 0; g < 6; ++g)                             \
      DST[g] = MFMA(ax1, Bih[g][1], MFMA(ax0, Bih[g][0], biasQ[g]));          \
  }

  f32x4 xaA0[6], xaA1[6], xaB0[6], xaB1[6];
  LOADXGA(4) LOADXGB(4)
  XACOMPA(xaA0) XACOMPB(xaB0)    // xa for steps 4..7
  LOADXGA(8) LOADXGB(8)          // x for steps 8..11

  // ---- one dual-chain step: XA/XB = xa arrays, R = comp literal, T = t ----
#define STEP2(XA, XB, R, T) {                                                 \
    /* gates A */                                                             \
    float rtA0 = aa0 * GVa[0][0] + aa1 * GVa[1][0] + aa2 * GVa[2][0];         \
    float rtA1 = aa0 * GVa[0][1] + aa1 * GVa[1][1] + aa2 * GVa[2][1];         \
    float rtA2 = aa0 * GVa[0][2] + aa1 * GVa[1][2] + aa2 * GVa[2][2];         \
    float rtA3 = aa0 * GVa[0][3] + aa1 * GVa[1][3] + aa2 * GVa[2][3];         \
    float rtA4 = aa0 * GVa[0][4] + aa1 * GVa[1][4] + aa2 * GVa[2][4];         \
    float rtA5 = aa0 * GVa[0][5] + aa1 * GVa[1][5] + aa2 * GVa[2][5];         \
    float rgA0 = sigmoidf_(XA[0][R] + hprzA0 + rtA0);                         \
    float rgA1 = sigmoidf_(XA[1][R] + hprzA1 + rtA1);                         \
    float zgA0 = sigmoidf_(XA[2][R] + hprzA2 + rtA2);                         \
    float zgA1 = sigmoidf_(XA[3][R] + hprzA3 + rtA3);                         \
    float ngA0 = tanhf_(XA[4][R] + rtA4 + rgA0 * hphnA0);                     \
    float ngA1 = tanhf_(XA[5][R] + rtA5 + rgA1 * hphnA1);                     \
    float hA0 = (1.0f - zgA0) * ngA0 + zgA0 * hA0p;                           \
    float hA1 = (1.0f - zgA1) * ngA1 + zgA1 * hA1p;                           \
    hA0p = hA0; hA1p = hA1;                                                   \
    /* gates B */                                                             \
    float rtB0 = ab0 * GVb[0][0] + ab1 * GVb[1][0] + ab2 * GVb[2][0];         \
    float rtB1 = ab0 * GVb[0][1] + ab1 * GVb[1][1] + ab2 * GVb[2][1];         \
    float rtB2 = ab0 * GVb[0][2] + ab1 * GVb[1][2] + ab2 * GVb[2][2];         \
    float rtB3 = ab0 * GVb[0][3] + ab1 * GVb[1][3] + ab2 * GVb[2][3];         \
    float rtB4 = ab0 * GVb[0][4] + ab1 * GVb[1][4] + ab2 * GVb[2][4];         \
    float rtB5 = ab0 * GVb[0][5] + ab1 * GVb[1][5] + ab2 * GVb[2][5];         \
    float rgB0 = sigmoidf_(XB[0][R] + hprzB0 + rtB0);                         \
    float rgB1 = sigmoidf_(XB[1][R] + hprzB1 + rtB1);                         \
    float zgB0 = sigmoidf_(XB[2][R] + hprzB2 + rtB2);                         \
    float zgB1 = sigmoidf_(XB[3][R] + hprzB3 + rtB3);                         \
    float ngB0 = tanhf_(XB[4][R] + rtB4 + rgB0 * hphnB0);                     \
    float ngB1 = tanhf_(XB[5][R] + rtB5 + rgB1 * hphnB1);                     \
    float hB0 = (1.0f - zgB0) * ngB0 + zgB0 * hB0p;                           \
    float hB1 = (1.0f - zgB1) * ngB1 + zgB1 * hB1p;                           \
    hB0p = hB0; hB1p = hB1;                                                   \
    /* h transport (both chains' bpermutes in flight together) */             \
    uint32_t hpkA = cvtpk_(hA0, hA1);                                         \
    uint32_t hpkB = cvtpk_(hB0, hB1);                                         \
    uint32_t fA0 = (uint32_t)__builtin_amdgcn_ds_bpermute(bp0, (int)hpkA);    \
    uint32_t fA1 = (uint32_t)__builtin_amdgcn_ds_bpermute(bp1, (int)hpkA);    \
    uint32_t fA2 = (uint32_t)__builtin_amdgcn_ds_bpermute(bp2, (int)hpkA);    \
    uint32_t fA3 = (uint32_t)__builtin_amdgcn_ds_bpermute(bp3, (int)hpkA);    \
    uint32_t fB0 = (uint32_t)__builtin_amdgcn_ds_bpermute(bp0, (int)hpkB);    \
    uint32_t fB1 = (uint32_t)__builtin_amdgcn_ds_bpermute(bp1, (int)hpkB);    \
    uint32_t fB2 = (uint32_t)__builtin_amdgcn_ds_bpermute(bp2, (int)hpkB);    \
    uint32_t fB3 = (uint32_t)__builtin_amdgcn_ds_bpermute(bp3, (int)hpkB);    \
    bf16x8 hAf = frag4(fA0, fA1, fA2, fA3);                                   \
    float oA;                                                                 \
    { f32x4 d_;                                                               \
      d_ = MFMA(hAf, BhhS[0], Zq);    hprzA0 = d_[0];                         \
      d_ = MFMA(hAf, BhhS[1], Zq);    hprzA1 = d_[0];                         \
      d_ = MFMA(hAf, BhhS[2], Zq);    hprzA2 = d_[0];                         \
      d_ = MFMA(hAf, BhhS[3], Zq);    hprzA3 = d_[0];                         \
      d_ = MFMA(hAf, BhhS[4], bhnQ0); hphnA0 = d_[0];                         \
      d_ = MFMA(hAf, BhhS[5], bhnQ1); hphnA1 = d_[0];                         \
      d_ = MFMA(hAf, BoS,     boQ);   oA = d_[0];                             \
    }                                                                         \
    bf16x8 hBf = frag4(fB0, fB1, fB2, fB3);                                   \
    float oB;                                                                 \
    { f32x4 d_;                                                               \
      d_ = MFMA(hBf, BhhS[0], Zq);    hprzB0 = d_[0];                         \
      d_ = MFMA(hBf, BhhS[1], Zq);    hprzB1 = d_[0];                         \
      d_ = MFMA(hBf, BhhS[2], Zq);    hprzB2 = d_[0];                         \
      d_ = MFMA(hBf, BhhS[3], Zq);    hprzB3 = d_[0];                         \
      d_ = MFMA(hBf, BhhS[4], bhnQ0); hphnB0 = d_[0];                         \
      d_ = MFMA(hBf, BhhS[5], bhnQ1); hphnB1 = d_[0];                         \
      d_ = MFMA(hBf, BoS,     boQ);   oB = d_[0];                             \
    }                                                                         \
    /* attention A -> a_s(t+1)  (no-max softmax; |p| small by construction) */\
    float paA0 = hA0 * Ma0[0] + hA1 * Ma1[0];                                 \
    float paA1 = hA0 * Ma0[1] + hA1 * Ma1[1];                                 \
    float paA2 = hA0 * Ma0[2] + hA1 * Ma1[2];                                 \
    paA0 = rowsum16(paA0) + Cqa[0];                                           \
    paA1 = rowsum16(paA1) + Cqa[1];                                           \
    paA2 = rowsum16(paA2) + Cqa[2];                                           \
    float eA0 = __expf(paA0), eA1 = __expf(paA1), eA2 = __expf(paA2);         \
    float invA = rcpf_(eA0 + eA1 + eA2);                                      \
    aa0 = eA0 * invA; aa1 = eA1 * invA; aa2 = eA2 * invA;                     \
    /* attention B */                                                         \
    float paB0 = hB0 * Mb0[0] + hB1 * Mb1[0];                                 \
    float paB1 = hB0 * Mb0[1] + hB1 * Mb1[1];                                 \
    float paB2 = hB0 * Mb0[2] + hB1 * Mb1[2];                                 \
    paB0 = rowsum16(paB0) + Cqb[0];                                           \
    paB1 = rowsum16(paB1) + Cqb[1];                                           \
    paB2 = rowsum16(paB2) + Cqb[2];                                           \
    float eB0 = __expf(paB0), eB1 = __expf(paB1), eB2 = __expf(paB2);         \
    float invB = rcpf_(eB0 + eB1 + eB2);                                      \
    ab0 = eB0 * invB; ab1 = eB1 * invB; ab2 = eB2 * invB;                     \
    /* direct stores (fire-and-forget) */                                     \
    hidWA[(T) * NH]      = hA0;                                               \
    hidWA[(T) * NH + 16] = hA1;                                               \
    outWA[(T) * NO]      = oA;                                                \
    hidWB[(T) * NH]      = hB0;                                               \
    hidWB[(T) * NH + 16] = hB1;                                               \
    outWB[(T) * NO]      = oB;                                                \
  }

#define GROUP2(TT, XAc, XAn, XBc, XBn, DONEXT, DOPF) {                        \
    if (DONEXT) { XACOMPA(XAn) XACOMPB(XBn) }                                 \
    if (DOPF)   { LOADXGA((TT) + 8) LOADXGB((TT) + 8) }                       \
    STEP2(XAc, XBc, 0, (TT) + 0)                                              \
    STEP2(XAc, XBc, 1, (TT) + 1)                                              \
    STEP2(XAc, XBc, 2, (TT) + 2)                                              \
    STEP2(XAc, XBc, 3, (TT) + 3)                                              \
  }

  // =========================================================================
  // Steady state t = 4..511: 31 superblocks of 16 + tail of 12.
  // =========================================================================
  for (int tb = 4; tb < 500; tb += 16) {
    GROUP2(tb + 0,  xaA0, xaA1, xaB0, xaB1, 1, 1)
    GROUP2(tb + 4,  xaA1, xaA0, xaB1, xaB0, 1, 1)
    GROUP2(tb + 8,  xaA0, xaA1, xaB0, xaB1, 1, 1)
    GROUP2(tb + 12, xaA1, xaA0, xaB1, xaB0, 1, 1)
  }
  {
    GROUP2(500, xaA0, xaA1, xaB0, xaB1, 1, 1)   // refill loads x508..x511
    GROUP2(504, xaA1, xaA0, xaB1, xaB0, 1, 0)   // xa(508..511); no refill
    GROUP2(508, xaA0, xaA1, xaB0, xaB1, 0, 0)   // consume; nothing ahead
  }
#undef STEP2
#undef GROUP2
#undef LOADXGA
#undef LOADXGB
#undef XACOMPA
#undef XACOMPB
}

extern "C" void kernel_launch(void* const* d_in, const int* in_sizes, int n_in,
                              void* d_out, int out_size, void* d_ws, size_t ws_size,
                              hipStream_t stream) {
  (void)in_sizes; (void)n_in; (void)out_size; (void)d_ws; (void)ws_size;
  const float* inputs   = (const float*)d_in[0];
  const float* w_ih     = (const float*)d_in[1];
  const float* w_hh     = (const float*)d_in[2];
  const float* b_ih     = (const float*)d_in[3];
  const float* b_hh     = (const float*)d_in[4];
  const float* W_key    = (const float*)d_in[5];
  const float* b_key    = (const float*)d_in[6];
  const float* W_query  = (const float*)d_in[7];
  const float* b_query  = (const float*)d_in[8];
  const float* W_value  = (const float*)d_in[9];
  const float* b_value  = (const float*)d_in[10];
  const float* W_recall = (const float*)d_in[11];
  const float* b_recall = (const float*)d_in[12];
  const float* W_out    = (const float*)d_in[13];
  const float* b_out    = (const float*)d_in[14];
  float* out = (float*)d_out;

  kvmr_kernel<<<dim3(128), dim3(128), 0, stream>>>(
      inputs, w_ih, w_hh, b_ih, b_hh, W_key, b_key, W_query, b_query,
      W_value, b_value, W_recall, b_recall, W_out, b_out, out);
}

// Round 13
// 574.408 us; speedup vs baseline: 1.3002x; 1.3002x over previous
//
#include <hip/hip_runtime.h>

// ---------------------------------------------------------------------------
// KeyValueMemoryRecallNet, R8: R6 base (measured 295us) + R7 algebra + shadow.
//   - 128 blocks x 256 threads (4 waves; wave w owns rows 4q4+w). Single
//     chain per wave — R7 proved dual-chain loses (1.33x overlap < 2x work).
//   - GV-fold: retr eliminated; gate g gets brc[g] (in biasQ) +
//     sum_s a_s*GV[s][g] where a_s are softmax weights. One dependency
//     level shorter than retr.
//   - No-max steady softmax (|p| <= ~5, exp-safe; prologue keeps masked form).
//   - Attention placed BETWEEN bpermute issue and MFMA consumption: its
//     ~150-cyc VALU chain fills the LDS transport latency that R6 exposed.
//   - Direct per-step stores (no batching buffers).
//   - Carries R6: sigma-order bpermute h-transport, 4-steps-per-MFMA xa
//     packing, persistent C-quads.
//
// MFMA 16x16x32 bf16 layouts (validated in R1):
//   A-frag: lane l holds A[row = l%16][k-slot j]
//   B-frag: lane l holds B[k-slot j][col = l%16]
//   C/D   : lane l holds D[row = 4*(l/16)+r][col = l%16]
// sigma k-order (h path): slot j of lane (q4,c) <-> k = 4*q4 + (j>>1) + 16*(j&1).
// bpermute: dest lane (q4,c) pulls f_i from source lane 16*(c>>2)+4*q4+i, which
// holds pack(h[4*(c>>2)+w][4q4+i], h[...][4q4+i+16]) -> A[row c] = h[4*(c>>2)+w],
// D[4q4+r][c] = gh[own row 4q4+w][col c] for all r (comp 0 used).
// ---------------------------------------------------------------------------

typedef __attribute__((ext_vector_type(4))) float f32x4;
typedef __attribute__((ext_vector_type(8))) __bf16 bf16x8;

#define NB 2048
#define SL 512
#define NIN 64
#define NH 32
#define NO 16

__device__ __forceinline__ float rcpf_(float x) { return __builtin_amdgcn_rcpf(x); }
__device__ __forceinline__ float sigmoidf_(float x) {
  return rcpf_(1.0f + __expf(-x));
}
__device__ __forceinline__ float tanhf_(float x) {
  return 1.0f - 2.0f * rcpf_(__expf(2.0f * x) + 1.0f);
}
__device__ __forceinline__ f32x4 splat4(float v) {
  f32x4 r; r[0] = v; r[1] = v; r[2] = v; r[3] = v; return r;
}

// DPP rotate-add reduction within each 16-lane row (groups == same l>>4).
template <int CTRL>
__device__ __forceinline__ float dpp_add_(float v) {
  int p = __builtin_amdgcn_update_dpp(0, __float_as_int(v), CTRL, 0xF, 0xF, true);
  return v + __int_as_float(p);
}
__device__ __forceinline__ float rowsum16(float v) {
  v = dpp_add_<0x121>(v);  // row_ror:1
  v = dpp_add_<0x122>(v);  // row_ror:2
  v = dpp_add_<0x124>(v);  // row_ror:4
  v = dpp_add_<0x128>(v);  // row_ror:8
  return v;
}

__device__ __forceinline__ uint32_t cvtpk_(float lo, float hi) {
  uint32_t r;
  asm("v_cvt_pk_bf16_f32 %0, %1, %2" : "=v"(r) : "v"(lo), "v"(hi));
  return r;
}

__device__ __forceinline__ bf16x8 frag4(uint32_t a, uint32_t b, uint32_t c, uint32_t d) {
  union { uint32_t u[4]; bf16x8 v; } x;
  x.u[0] = a; x.u[1] = b; x.u[2] = c; x.u[3] = d;
  return x.v;
}

// uniform-w component picks (one-time / prologue only)
__device__ __forceinline__ float pick4v(f32x4 v, int w) {
  float a = (w & 2) ? v[2] : v[0];
  float b = (w & 2) ? v[3] : v[1];
  return (w & 1) ? b : a;
}
__device__ __forceinline__ float pick4f(float a0, float a1, float a2, float a3, int w) {
  float a = (w & 2) ? a2 : a0;
  float b = (w & 2) ? a3 : a1;
  return (w & 1) ? b : a;
}

// standard-order B-frag of W^T (y = x @ W^T): B[k][col] = W[col][k].
__device__ __forceinline__ bf16x8 ldfrag(const float* __restrict__ W, int indim,
                                         int row, int k0) {
  bf16x8 r;
#pragma unroll
  for (int j = 0; j < 8; ++j) {
    int k = k0 + j;
    float w = (k < indim) ? W[row * indim + k] : 0.0f;
    r[j] = (__bf16)w;
  }
  return r;
}
// sigma-order B-frag (indim==32): slot j -> k = 4*q4 + (j>>1) + ((j&1) ? 16 : 0)
__device__ __forceinline__ bf16x8 ldfragS(const float* __restrict__ W, int row, int q4) {
  bf16x8 r;
#pragma unroll
  for (int j = 0; j < 8; ++j) {
    int k = 4 * q4 + (j >> 1) + ((j & 1) ? 16 : 0);
    r[j] = (__bf16)W[row * 32 + k];
  }
  return r;
}
// B-frag of W (y = x @ W): B[k][col] = W[k][col].
__device__ __forceinline__ bf16x8 ldfragT(const float* __restrict__ W, int ncol,
                                          int col, int k0) {
  bf16x8 r;
#pragma unroll
  for (int j = 0; j < 8; ++j) r[j] = (__bf16)W[(k0 + j) * ncol + col];
  return r;
}

#define MFMA(A, B, C) __builtin_amdgcn_mfma_f32_16x16x32_bf16((A), (B), (C), 0, 0, 0)

__global__ __launch_bounds__(256, 1)
void kvmr_kernel(const float* __restrict__ inputs,   // [2048][512][64]
                 const float* __restrict__ w_ih,     // [96][66]
                 const float* __restrict__ w_hh,     // [96][32]
                 const float* __restrict__ b_ih,     // [96]
                 const float* __restrict__ b_hh,     // [96]
                 const float* __restrict__ W_key,    // [64][32]
                 const float* __restrict__ b_key,    // [64]
                 const float* __restrict__ W_query,  // [64][32]
                 const float* __restrict__ b_query,  // [64]
                 const float* __restrict__ W_value,  // [64][32]
                 const float* __restrict__ b_value,  // [64]
                 const float* __restrict__ W_recall, // [2][64]
                 const float* __restrict__ b_recall, // [2]
                 const float* __restrict__ W_out,    // [16][32]
                 const float* __restrict__ b_out,    // [16]
                 float* __restrict__ out_all) {      // outputs | hiddens
  const int tid = threadIdx.x;
  const int l  = tid & 63;
  const int c  = l & 15;
  const int q4 = l >> 4;
  const int w  = tid >> 6;
  const int b0 = blockIdx.x * 16;

  __shared__ __align__(16) uint32_t h_pk[4][16 * 16];      // per-wave prologue relay (packed)
  __shared__ __align__(16) __bf16 kv_pro[4][3][16 * 64];   // per-wave fold relay

  // ---- weights as register-resident B-fragments ----
  bf16x8 Bih[6][2];       // standard order (A = x from global, standard k)
  bf16x8 BhhS[6];         // sigma order (A = h via bpermute/packed relay)
#pragma unroll
  for (int g = 0; g < 6; ++g) {
#pragma unroll
    for (int kc = 0; kc < 2; ++kc)
      Bih[g][kc] = ldfrag(w_ih, 66, 16 * g + c, 32 * kc + 8 * q4);
    BhhS[g] = ldfragS(w_hh, 16 * g + c, q4);
  }
  bf16x8 BqS[4], BkS[4], BvS[4];
#pragma unroll
  for (int g = 0; g < 4; ++g) {
    BqS[g] = ldfragS(W_query, 16 * g + c, q4);
    BkS[g] = ldfragS(W_key,   16 * g + c, q4);
    BvS[g] = ldfragS(W_value, 16 * g + c, q4);
  }
  bf16x8 BoS = ldfragS(W_out, c, q4);

  float wih64[6], wih65[6];
#pragma unroll
  for (int g = 0; g < 6; ++g) {
    wih64[g] = w_ih[(16 * g + c) * 66 + 64];
    wih65[g] = w_ih[(16 * g + c) * 66 + 65];
  }
  float wr0f[4], wr1f[4];
#pragma unroll
  for (int g = 0; g < 4; ++g) {
    wr0f[g] = W_recall[16 * g + c];
    wr1f[g] = W_recall[64 + 16 * g + c];
  }

  float bias_rz[4], bias_xn[2], bias_hn[2];
#pragma unroll
  for (int g = 0; g < 4; ++g) bias_rz[g] = b_ih[16 * g + c] + b_hh[16 * g + c];
#pragma unroll
  for (int gg = 0; gg < 2; ++gg) {
    bias_xn[gg] = b_ih[64 + 16 * gg + c];
    bias_hn[gg] = b_hh[64 + 16 * gg + c];
  }
  float bq4[4], bk4[4], bv4[4];
#pragma unroll
  for (int g = 0; g < 4; ++g) {
    bq4[g] = b_query[16 * g + c];
    bk4[g] = b_key[16 * g + c];
    bv4[g] = b_value[16 * g + c];
  }
  float bo1 = b_out[c];
  float br0 = b_recall[0], br1 = b_recall[1];

  float* outW = out_all + (size_t)(b0 + 4 * q4 + w) * SL * NO + c;
  float* hidW = out_all + (size_t)NB * SL * NO + (size_t)(b0 + 4 * q4 + w) * SL * NH + c;

  // ---- prologue state ----
  f32x4 hD0 = splat4(0.0f), hD1 = splat4(0.0f);
  f32x4 keysR[3][4], valsR[3][4];
#pragma unroll
  for (int s = 0; s < 3; ++s)
#pragma unroll
    for (int g = 0; g < 4; ++g) { keysR[s][g] = splat4(0.0f); valsR[s][g] = splat4(0.0f); }

  f32x4 hPartRZ[4], hPartHN[2];
#pragma unroll
  for (int g = 0; g < 4; ++g) hPartRZ[g] = splat4(bias_rz[g]);
#pragma unroll
  for (int gg = 0; gg < 2; ++gg) hPartHN[gg] = splat4(bias_hn[gg]);
  float retr0c[4] = {0.f, 0.f, 0.f, 0.f};
  float retr1c[4] = {0.f, 0.f, 0.f, 0.f};

  // ---- prologue x double prefetch (rows b0+c; all 16 rows genuine) ----
  const float* xp = inputs + (size_t)(b0 + c) * (SL * NIN) + 8 * q4;
  f32x4 xb[2][4];
#pragma unroll
  for (int p = 0; p < 2; ++p) {
    const float* xq = xp + p * NIN;
    xb[p][0] = *(const f32x4*)(xq + 0);
    xb[p][1] = *(const f32x4*)(xq + 4);
    xb[p][2] = *(const f32x4*)(xq + 32);
    xb[p][3] = *(const f32x4*)(xq + 36);
  }

  // =========================================================================
  // Prologue: t = 0,1,2 — redundant per wave, private LDS, no sync.
  // =========================================================================
#pragma unroll
  for (int t = 0; t < 3; ++t) {
    const int pb = t & 1;
    bf16x8 ax0, ax1;
#pragma unroll
    for (int j = 0; j < 4; ++j) {
      ax0[j]     = (__bf16)xb[pb][0][j];
      ax0[4 + j] = (__bf16)xb[pb][1][j];
      ax1[j]     = (__bf16)xb[pb][2][j];
      ax1[4 + j] = (__bf16)xb[pb][3][j];
    }
    {
      const float* xq = xp + (t + 2) * NIN;
      xb[pb][0] = *(const f32x4*)(xq + 0);
      xb[pb][1] = *(const f32x4*)(xq + 4);
      xb[pb][2] = *(const f32x4*)(xq + 32);
      xb[pb][3] = *(const f32x4*)(xq + 36);
    }

    f32x4 accRZ[4], accXN[2];
#pragma unroll
    for (int g = 0; g < 4; ++g) {
      f32x4 a = hPartRZ[g];
#pragma unroll
      for (int r = 0; r < 4; ++r) a[r] += retr0c[r] * wih64[g] + retr1c[r] * wih65[g];
      a = MFMA(ax0, Bih[g][0], a);
      a = MFMA(ax1, Bih[g][1], a);
      accRZ[g] = a;
    }
#pragma unroll
    for (int gg = 0; gg < 2; ++gg) {
      f32x4 a = splat4(bias_xn[gg]);
#pragma unroll
      for (int r = 0; r < 4; ++r) a[r] += retr0c[r] * wih64[4 + gg] + retr1c[r] * wih65[4 + gg];
      a = MFMA(ax0, Bih[4 + gg][0], a);
      a = MFMA(ax1, Bih[4 + gg][1], a);
      accXN[gg] = a;
    }

    f32x4 hn0, hn1;
#pragma unroll
    for (int r = 0; r < 4; ++r) {
      float rg0 = sigmoidf_(accRZ[0][r]);
      float zg0 = sigmoidf_(accRZ[2][r]);
      float ng0 = tanhf_(accXN[0][r] + rg0 * hPartHN[0][r]);
      hn0[r] = (1.0f - zg0) * ng0 + zg0 * hD0[r];
      float rg1 = sigmoidf_(accRZ[1][r]);
      float zg1 = sigmoidf_(accRZ[3][r]);
      float ng1 = tanhf_(accXN[1][r] + rg1 * hPartHN[1][r]);
      hn1[r] = (1.0f - zg1) * ng1 + zg1 * hD1[r];
    }
    hD0 = hn0; hD1 = hn1;

    hidW[t * NH]      = pick4v(hn0, w);
    hidW[t * NH + 16] = pick4v(hn1, w);
    // packed sigma relay: write pair u32, read b128 of 4 consecutive pairs
#pragma unroll
    for (int r = 0; r < 4; ++r)
      h_pk[w][(4 * q4 + r) * 16 + c] = cvtpk_(hn0[r], hn1[r]);
    bf16x8 hA = *(const bf16x8*)&h_pk[w][c * 16 + 4 * q4];

#pragma unroll
    for (int g = 0; g < 4; ++g) hPartRZ[g] = MFMA(hA, BhhS[g], splat4(bias_rz[g]));
#pragma unroll
    for (int gg = 0; gg < 2; ++gg) hPartHN[gg] = MFMA(hA, BhhS[4 + gg], splat4(bias_hn[gg]));
    f32x4 oT = MFMA(hA, BoS, splat4(bo1));
    outW[t * NO] = pick4v(oT, w);

    f32x4 qT[4], kT[4], vT[4];
#pragma unroll
    for (int g = 0; g < 4; ++g) {
      qT[g] = MFMA(hA, BqS[g], splat4(bq4[g]));
      kT[g] = MFMA(hA, BkS[g], splat4(bk4[g]));
      vT[g] = MFMA(hA, BvS[g], splat4(bv4[g]));
    }

    // attention over slots < t (scores on pre-write memory); masked max form
#pragma unroll
    for (int r = 0; r < 4; ++r) {
      float d0 = qT[0][r] * keysR[0][0][r] + qT[1][r] * keysR[0][1][r] +
                 qT[2][r] * keysR[0][2][r] + qT[3][r] * keysR[0][3][r];
      float d1 = qT[0][r] * keysR[1][0][r] + qT[1][r] * keysR[1][1][r] +
                 qT[2][r] * keysR[1][2][r] + qT[3][r] * keysR[1][3][r];
      float s0 = (t > 0) ? rowsum16(d0) : -1e30f;
      float s1 = (t > 1) ? rowsum16(d1) : -1e30f;
      float s2 = -1e30f;
      float mx = fmaxf(s0, fmaxf(s1, s2));
      float e0 = __expf(s0 - mx), e1 = __expf(s1 - mx), e2 = __expf(s2 - mx);
      float inv = rcpf_(e0 + e1 + e2);
      float u0 = 0.f, u1 = 0.f;
#pragma unroll
      for (int g = 0; g < 4; ++g) {
        float rd = (e0 * valsR[0][g][r] + e1 * valsR[1][g][r] + e2 * valsR[2][g][r]) * inv;
        u0 += rd * wr0f[g];
        u1 += rd * wr1f[g];
      }
      u0 = rowsum16(u0);
      u1 = rowsum16(u1);
      retr0c[r] = (t > 0) ? (u0 + br0) : 0.0f;
      retr1c[r] = (t > 0) ? (u1 + br1) : 0.0f;
    }

#pragma unroll
    for (int g = 0; g < 4; ++g) { keysR[t][g] = kT[g]; valsR[t][g] = vT[g]; }
  }

  // =========================================================================
  // Fold (memory frozen after t=2): M = keys@Wq, Cq = bq.keys, VR = vals.Wr^T
  // =========================================================================
#pragma unroll
  for (int s = 0; s < 3; ++s)
#pragma unroll
    for (int g = 0; g < 4; ++g)
#pragma unroll
      for (int r = 0; r < 4; ++r)
        kv_pro[w][s][(4 * q4 + r) * 64 + 16 * g + c] = (__bf16)keysR[s][g][r];

  bf16x8 Bwq[2][2];
#pragma unroll
  for (int ch = 0; ch < 2; ++ch)
#pragma unroll
    for (int ct = 0; ct < 2; ++ct)
      Bwq[ch][ct] = ldfragT(W_query, 32, 16 * ct + c, 32 * ch + 8 * q4);

  float M0c[3][4], M1c[3][4], Cq[3][4], VRa[3][4], VRb[3][4];
#pragma unroll
  for (int s = 0; s < 3; ++s) {
    const bf16x8 ak0 = *(const bf16x8*)&kv_pro[w][s][c * 64 + 8 * q4];
    const bf16x8 ak1 = *(const bf16x8*)&kv_pro[w][s][c * 64 + 32 + 8 * q4];
    f32x4 m0 = MFMA(ak1, Bwq[1][0], MFMA(ak0, Bwq[0][0], splat4(0.0f)));
    f32x4 m1 = MFMA(ak1, Bwq[1][1], MFMA(ak0, Bwq[0][1], splat4(0.0f)));
#pragma unroll
    for (int r = 0; r < 4; ++r) {
      M0c[s][r] = m0[r];
      M1c[s][r] = m1[r];
      Cq[s][r] = rowsum16(keysR[s][0][r] * bq4[0] + keysR[s][1][r] * bq4[1] +
                          keysR[s][2][r] * bq4[2] + keysR[s][3][r] * bq4[3]);
      VRa[s][r] = rowsum16(valsR[s][0][r] * wr0f[0] + valsR[s][1][r] * wr0f[1] +
                           valsR[s][2][r] * wr0f[2] + valsR[s][3][r] * wr0f[3]);
      VRb[s][r] = rowsum16(valsR[s][0][r] * wr1f[0] + valsR[s][1][r] * wr1f[1] +
                           valsR[s][2][r] * wr1f[2] + valsR[s][3][r] * wr1f[3]);
    }
  }

  // ---- W slices ----
  float M0w[3], M1w[3], Cqw[3], VAw[3], VBw[3];
#pragma unroll
  for (int s = 0; s < 3; ++s) {
    M0w[s] = pick4f(M0c[s][0], M0c[s][1], M0c[s][2], M0c[s][3], w);
    M1w[s] = pick4f(M1c[s][0], M1c[s][1], M1c[s][2], M1c[s][3], w);
    Cqw[s] = pick4f(Cq[s][0],  Cq[s][1],  Cq[s][2],  Cq[s][3],  w);
    VAw[s] = pick4f(VRa[s][0], VRa[s][1], VRa[s][2], VRa[s][3], w);
    VBw[s] = pick4f(VRb[s][0], VRb[s][1], VRb[s][2], VRb[s][3], w);
  }

  // ---- GV fold: gate g gets brc[g] + sum_s a_s * GVw[s][g] ----
  float GVw[3][6], brc[6];
#pragma unroll
  for (int g = 0; g < 6; ++g) {
    brc[g] = br0 * wih64[g] + br1 * wih65[g];
#pragma unroll
    for (int s = 0; s < 3; ++s)
      GVw[s][g] = VAw[s] * wih64[g] + VBw[s] * wih65[g];
  }

  // ---- persistent MFMA C-quads (brc folded into biasQ via xa path) ----
  const f32x4 Zq = splat4(0.0f);
  f32x4 biasQ[6];
#pragma unroll
  for (int g = 0; g < 4; ++g) biasQ[g] = splat4(bias_rz[g] + brc[g]);
  biasQ[4] = splat4(bias_xn[0] + brc[4]);
  biasQ[5] = splat4(bias_xn[1] + brc[5]);
  const f32x4 bhnQ0 = splat4(bias_hn[0]);
  const f32x4 bhnQ1 = splat4(bias_hn[1]);
  const f32x4 boQ   = splat4(bo1);

  // ---- t = 3 closed form (h_3 flushed to 0) ----
  hidW[3 * NH]      = 0.0f;
  hidW[3 * NH + 16] = 0.0f;
  outW[3 * NO]      = bo1;

  float a0, a1, a2;
  {
    float e0 = __expf(Cqw[0]), e1 = __expf(Cqw[1]), e2 = __expf(Cqw[2]);
    float inv = rcpf_(e0 + e1 + e2);
    a0 = e0 * inv; a1 = e1 * inv; a2 = e2 * inv;
  }

  float hprz0 = 0.0f, hprz1 = 0.0f, hprz2 = 0.0f, hprz3 = 0.0f;
  float hphn0 = bias_hn[0], hphn1 = bias_hn[1];
  float h0p = 0.0f, h1p = 0.0f;

  // bpermute source-lane byte indices: dst lane l pulls from 16*((l>>2)&3)+4*(l>>4)+i
  const int bp0 = 4 * (16 * ((l >> 2) & 3) + 4 * (l >> 4));
  const int bp1 = bp0 + 4;
  const int bp2 = bp0 + 8;
  const int bp3 = bp0 + 12;

  // ---- steady x pipeline: lane (q4,c) loads x[row b0+4*(c>>2)+w][step T+(c&3)]
  const float* xgp = inputs + (size_t)(b0 + 4 * (c >> 2) + w) * (SL * NIN) +
                     (size_t)(c & 3) * NIN + 8 * q4;
  f32x4 xg[4];
#define LOADXG(T) {                                                           \
    const float* q_ = xgp + (size_t)(T) * NIN;                                \
    xg[0] = *(const f32x4*)(q_ + 0);                                          \
    xg[1] = *(const f32x4*)(q_ + 4);                                          \
    xg[2] = *(const f32x4*)(q_ + 32);                                         \
    xg[3] = *(const f32x4*)(q_ + 36);                                         \
  }
#define XACOMP(DST) {                                                         \
    bf16x8 ax0, ax1;                                                          \
    _Pragma("unroll") for (int j = 0; j < 4; ++j) {                           \
      ax0[j]     = (__bf16)xg[0][j];                                          \
      ax0[4 + j] = (__bf16)xg[1][j];                                          \
      ax1[j]     = (__bf16)xg[2][j];                                          \
      ax1[4 + j] = (__bf16)xg[3][j];                                          \
    }                                                                         \
    _Pragma("unroll") for (int g = 0; g < 6; ++g)                             \
      DST[g] = MFMA(ax1, Bih[g][1], MFMA(ax0, Bih[g][0], biasQ[g]));          \
  }

  f32x4 xaA[6], xaB[6];
  LOADXG(4)
  XACOMP(xaA)        // xa for steps 4..7 (comp r = step 4+r), bias+brc included
  LOADXG(8)          // x for steps 8..11

  // ---- one step: XC = xa array, R = comp literal, T = time ----
  // Order: gates -> h -> cvtpk/bpermute ISSUE -> attention (fills LDS wait)
  //        -> MFMA -> direct stores.
#define STEP(XC, R, T) {                                                      \
    float rt0 = a0 * GVw[0][0] + a1 * GVw[1][0] + a2 * GVw[2][0];             \
    float rt1 = a0 * GVw[0][1] + a1 * GVw[1][1] + a2 * GVw[2][1];             \
    float rt2 = a0 * GVw[0][2] + a1 * GVw[1][2] + a2 * GVw[2][2];             \
    float rt3 = a0 * GVw[0][3] + a1 * GVw[1][3] + a2 * GVw[2][3];             \
    float rt4 = a0 * GVw[0][4] + a1 * GVw[1][4] + a2 * GVw[2][4];             \
    float rt5 = a0 * GVw[0][5] + a1 * GVw[1][5] + a2 * GVw[2][5];             \
    float rg0 = sigmoidf_(XC[0][R] + hprz0 + rt0);                            \
    float rg1 = sigmoidf_(XC[1][R] + hprz1 + rt1);                            \
    float zg0 = sigmoidf_(XC[2][R] + hprz2 + rt2);                            \
    float zg1 = sigmoidf_(XC[3][R] + hprz3 + rt3);                            \
    float ng0 = tanhf_(XC[4][R] + rt4 + rg0 * hphn0);                         \
    float ng1 = tanhf_(XC[5][R] + rt5 + rg1 * hphn1);                         \
    float h0 = (1.0f - zg0) * ng0 + zg0 * h0p;                                \
    float h1 = (1.0f - zg1) * ng1 + zg1 * h1p;                                \
    h0p = h0; h1p = h1;                                                       \
    uint32_t hpk = cvtpk_(h0, h1);                                            \
    uint32_t f0 = (uint32_t)__builtin_amdgcn_ds_bpermute(bp0, (int)hpk);      \
    uint32_t f1 = (uint32_t)__builtin_amdgcn_ds_bpermute(bp1, (int)hpk);      \
    uint32_t f2 = (uint32_t)__builtin_amdgcn_ds_bpermute(bp2, (int)hpk);      \
    uint32_t f3 = (uint32_t)__builtin_amdgcn_ds_bpermute(bp3, (int)hpk);      \
    /* attention in the LDS-transport shadow (register-only VALU) */          \
    float p0 = h0 * M0w[0] + h1 * M1w[0];                                     \
    float p1 = h0 * M0w[1] + h1 * M1w[1];                                     \
    float p2 = h0 * M0w[2] + h1 * M1w[2];                                     \
    p0 = rowsum16(p0) + Cqw[0];                                               \
    p1 = rowsum16(p1) + Cqw[1];                                               \
    p2 = rowsum16(p2) + Cqw[2];                                               \
    float e0 = __expf(p0), e1 = __expf(p1), e2 = __expf(p2);                  \
    float inv = rcpf_(e0 + e1 + e2);                                          \
    a0 = e0 * inv; a1 = e1 * inv; a2 = e2 * inv;                              \
    bf16x8 hA = frag4(f0, f1, f2, f3);                                        \
    float oo;                                                                 \
    { f32x4 d_;                                                               \
      d_ = MFMA(hA, BhhS[0], Zq);    hprz0 = d_[0];                           \
      d_ = MFMA(hA, BhhS[1], Zq);    hprz1 = d_[0];                           \
      d_ = MFMA(hA, BhhS[2], Zq);    hprz2 = d_[0];                           \
      d_ = MFMA(hA, BhhS[3], Zq);    hprz3 = d_[0];                           \
      d_ = MFMA(hA, BhhS[4], bhnQ0); hphn0 = d_[0];                           \
      d_ = MFMA(hA, BhhS[5], bhnQ1); hphn1 = d_[0];                           \
      d_ = MFMA(hA, BoS,     boQ);   oo = d_[0];                              \
    }                                                                         \
    hidW[(T) * NH]      = h0;                                                 \
    hidW[(T) * NH + 16] = h1;                                                 \
    outW[(T) * NO]      = oo;                                                 \
  }

  // ---- group of 4 steps: compute next-group xa, refill xg, run 4 STEPs ----
#define GROUP4(TT, XC, XN, DONEXT, DOPF) {                                    \
    if (DONEXT) { XACOMP(XN) }                                                \
    if (DOPF)   { LOADXG((TT) + 8) }                                          \
    STEP(XC, 0, (TT) + 0)                                                     \
    STEP(XC, 1, (TT) + 1)                                                     \
    STEP(XC, 2, (TT) + 2)                                                     \
    STEP(XC, 3, (TT) + 3)                                                     \
  }

  // =========================================================================
  // Steady state t = 4..511: 31 superblocks of 16 + tail of 12.
  // =========================================================================
  for (int tb = 4; tb < 500; tb += 16) {
    GROUP4(tb + 0,  xaA, xaB, 1, 1)
    GROUP4(tb + 4,  xaB, xaA, 1, 1)
    GROUP4(tb + 8,  xaA, xaB, 1, 1)
    GROUP4(tb + 12, xaB, xaA, 1, 1)
  }
  {
    GROUP4(500, xaA, xaB, 1, 1)   // refill loads x508..x511 (valid)
    GROUP4(504, xaB, xaA, 1, 0)   // XN = xa(508..511) from xg; no refill
    GROUP4(508, xaA, xaB, 0, 0)   // consume xa(508..511); nothing ahead
  }
#undef STEP
#undef GROUP4
#undef LOADXG
#undef XACOMP
}

extern "C" void kernel_launch(void* const* d_in, const int* in_sizes, int n_in,
                              void* d_out, int out_size, void* d_ws, size_t ws_size,
                              hipStream_t stream) {
  (void)in_sizes; (void)n_in; (void)out_size; (void)d_ws; (void)ws_size;
  const float* inputs   = (const float*)d_in[0];
  const float* w_ih     = (const float*)d_in[1];
  const float* w_hh     = (const float*)d_in[2];
  const float* b_ih     = (const float*)d_in[3];
  const float* b_hh     = (const float*)d_in[4];
  const float* W_key    = (const float*)d_in[5];
  const float* b_key    = (const float*)d_in[6];
  const float* W_query  = (const float*)d_in[7];
  const float* b_query  = (const float*)d_in[8];
  const float* W_value  = (const float*)d_in[9];
  const float* b_value  = (const float*)d_in[10];
  const float* W_recall = (const float*)d_in[11];
  const float* b_recall = (const float*)d_in[12];
  const float* W_out    = (const float*)d_in[13];
  const float* b_out    = (const float*)d_in[14];
  float* out = (float*)d_out;

  kvmr_kernel<<<dim3(128), dim3(256), 0, stream>>>(
      inputs, w_ih, w_hh, b_ih, b_hh, W_key, b_key, W_query, b_query,
      W_value, b_value, W_recall, b_recall, W_out, b_out, out);
}